// Round 1
// baseline (637.231 us; speedup 1.0000x reference)
//
#include <hip/hip_runtime.h>

// Problem constants (from reference):
//   N_NODES=4096, N_EDGES=131072, D_EDGE=128, N_HEADS=8
//   out = zeros(H, N, N); out[:, u, v] = (edge_attr @ W + b).T  (last-write-wins)
#define N_NODES 4096
#define N_EDGES 131072
#define D_EDGE  128
#define N_HEADS 8

// Pass B: record the winning (max) edge id per (u,v) cell, using output
// plane 0 (already zeroed) as the winner table. Edge ids stored as e+1 (>0),
// so signed int atomicMax over a zero field is correct.
__global__ void edgebias_winner(const int* __restrict__ edge_index,
                                int* __restrict__ out_plane0) {
    int e = blockIdx.x * blockDim.x + threadIdx.x;
    if (e >= N_EDGES) return;
    int u = edge_index[e];
    int v = edge_index[N_EDGES + e];
    atomicMax(&out_plane0[(size_t)u * N_NODES + v], e + 1);
}

// Pass C: the winning edge of each cell computes its 8 head scores and writes
// them to all 8 planes (overwriting its id in plane 0 with the real score).
__global__ void edgebias_scatter(const int* __restrict__ edge_index,
                                 const float* __restrict__ edge_attr,
                                 const float* __restrict__ W,
                                 const float* __restrict__ b,
                                 float* __restrict__ out) {
    __shared__ float Ws[D_EDGE * N_HEADS];   // 4 KB, [d][h] row-major
    __shared__ float bs[N_HEADS];
    for (int i = threadIdx.x; i < D_EDGE * N_HEADS; i += blockDim.x)
        Ws[i] = W[i];
    if (threadIdx.x < N_HEADS) bs[threadIdx.x] = b[threadIdx.x];
    __syncthreads();

    int e = blockIdx.x * blockDim.x + threadIdx.x;
    if (e >= N_EDGES) return;
    int u = edge_index[e];
    int v = edge_index[N_EDGES + e];
    size_t cell = (size_t)u * N_NODES + v;

    // Winner check: only the last-writing edge for this cell proceeds.
    const int* out_i = (const int*)out;
    if (out_i[cell] != e + 1) return;

    float acc[N_HEADS];
    #pragma unroll
    for (int h = 0; h < N_HEADS; ++h) acc[h] = bs[h];

    const float4* row = (const float4*)(edge_attr + (size_t)e * D_EDGE);
    #pragma unroll 8
    for (int j = 0; j < D_EDGE / 4; ++j) {
        float4 a = row[j];
        int d = j * 4;
        #pragma unroll
        for (int h = 0; h < N_HEADS; ++h) {
            acc[h] += a.x * Ws[(d + 0) * N_HEADS + h]
                    + a.y * Ws[(d + 1) * N_HEADS + h]
                    + a.z * Ws[(d + 2) * N_HEADS + h]
                    + a.w * Ws[(d + 3) * N_HEADS + h];
        }
    }

    #pragma unroll
    for (int h = 0; h < N_HEADS; ++h)
        out[(size_t)h * N_NODES * N_NODES + cell] = acc[h];
}

extern "C" void kernel_launch(void* const* d_in, const int* in_sizes, int n_in,
                              void* d_out, int out_size, void* d_ws, size_t ws_size,
                              hipStream_t stream) {
    const int*   edge_index = (const int*)  d_in[0];  // (2, E) int32
    const float* edge_attr  = (const float*)d_in[1];  // (E, 128) f32
    const float* W          = (const float*)d_in[2];  // (128, 8) f32
    const float* b          = (const float*)d_in[3];  // (8,) f32
    float* out = (float*)d_out;                       // (8, 4096, 4096) f32

    // Stage 1: zero the 512 MB output (graph-capturable memset node).
    size_t out_bytes = (size_t)N_HEADS * N_NODES * N_NODES * sizeof(float);
    hipMemsetAsync(d_out, 0, out_bytes, stream);

    // Stage 2: winner ids into plane 0.
    dim3 blk(256);
    dim3 grd((N_EDGES + 255) / 256);
    edgebias_winner<<<grd, blk, 0, stream>>>(edge_index, (int*)d_out);

    // Stage 3: winners compute scores and scatter to all 8 planes.
    edgebias_scatter<<<grd, blk, 0, stream>>>(edge_index, edge_attr, W, b, out);
}